// Round 4
// baseline (430.632 us; speedup 1.0000x reference)
//
#include <hip/hip_runtime.h>
#include <hip/hip_bf16.h>
#include <hip/hip_cooperative_groups.h>
#include <math.h>

namespace cg = cooperative_groups;

#define N_NODES 100000
#define N_EDGES 1600000
#define IN_FEATS 256
#define OUT_FEATS 64
#define NHEAD 4
#define F_TOT 256
#define ALPHA 0.2f

typedef __attribute__((ext_vector_type(8))) short short8;
typedef __attribute__((ext_vector_type(8))) unsigned short ush8;
typedef __attribute__((ext_vector_type(4))) float f32x4;

// ---------------- workspace layout (bytes) ----------------
#define OFF_HB    ((size_t)0)            // 51,200,000
#define OFF_HL    ((size_t)51200000)     // 1,600,000
#define OFF_HR    ((size_t)52800000)     // 1,600,000
#define OFF_CNT   ((size_t)54400000)     // 400,128
#define OFF_OFFS  ((size_t)54800128)     // 400,128
#define OFF_CUR   ((size_t)55200256)     // 400,128
#define OFF_CSORT ((size_t)55600384)     // 6,400,000
#define OFF_BSUM  ((size_t)62000384)     // 512
#define OFF_WT    ((size_t)62000896)     // 131,072

__device__ inline float bf2f(ushort u) { return __uint_as_float((uint)u << 16); }
__device__ inline ushort f2bf(float f) {
  __hip_bfloat16 b = __float2bfloat16(f);
  return *(ushort*)&b;
}

// ---------------- W transpose+cast ----------------
__global__ __launch_bounds__(256) void castT_W_kernel(const float* __restrict__ W,
                                                      ushort* __restrict__ Wt) {
  __shared__ float s[64][65];
  const int bi = blockIdx.x & 3;
  const int bj = blockIdx.x >> 2;
  const int tid = threadIdx.x;
  const int n0 = bi * 64, k0 = bj * 64;
  #pragma unroll
  for (int it = 0; it < 16; ++it) {
    int idx = it * 256 + tid;
    int r = idx >> 6, c = idx & 63;
    s[c][r] = W[(size_t)(k0 + r) * F_TOT + n0 + c];
  }
  __syncthreads();
  #pragma unroll
  for (int it = 0; it < 16; ++it) {
    int idx = it * 256 + tid;
    int nn = idx >> 6, kk = idx & 63;
    Wt[(size_t)(n0 + nn) * IN_FEATS + k0 + kk] = f2bf(s[nn][kk]);
  }
}

// ---------------- fused GEMM + hist ----------------
#define GBM 128
#define GBN 128
#define GBK 64
#define HIST_BLKS 512
#define NRBLK 782   // ceil(100000/128)

__global__ __launch_bounds__(256) void gemm_hist(const float* __restrict__ X,
                                                 const ushort* __restrict__ Bt,
                                                 ushort* __restrict__ hb,
                                                 const float* __restrict__ a_l,
                                                 const float* __restrict__ a_r,
                                                 float* __restrict__ hl,
                                                 float* __restrict__ hr, int M,
                                                 const int* __restrict__ row,
                                                 int* __restrict__ counts, int E) {
  if (blockIdx.x < HIST_BLKS) {
    int gtid = blockIdx.x * 256 + threadIdx.x;
    for (int i = gtid; i < E; i += HIST_BLKS * 256) atomicAdd(&counts[row[i]], 1);
    return;
  }
  const int g2 = blockIdx.x - HIST_BLKS;
  // XCD pair-swizzle: (rr,0) at gid g and (rr,1) at g+8 -> same XCD, L2-shared x tile
  const int rr = ((g2 >> 4) << 3) | (g2 & 7);
  const int cb = (g2 >> 3) & 1;
  if (rr >= NRBLK) return;

  __shared__ __align__(16) ushort As[GBM][GBK + 8];
  __shared__ __align__(16) ushort Bs[GBN][GBK + 8];
  const int row0 = rr * GBM;
  const int col0 = cb * GBN;
  const int tid = threadIdx.x;
  const int lane = tid & 63;
  const int wid = tid >> 6;
  const int wr = wid >> 1, wc = wid & 1;
  const int lr = lane & 15;
  const int kq = lane >> 4;

  f32x4 acc[4][4];
  #pragma unroll
  for (int i = 0; i < 4; ++i)
    #pragma unroll
    for (int j = 0; j < 4; ++j) acc[i][j] = (f32x4)(0.f);

  for (int k0 = 0; k0 < IN_FEATS; k0 += GBK) {
    short8 ar[4], br[4];
    #pragma unroll
    for (int ii = 0; ii < 4; ++ii) {
      int ch = ii * 256 + tid;
      int r = ch >> 3, cc = ch & 7;
      int gr = row0 + r;
      short8 v = (short8)(0);
      if (gr < M) {
        const float4 f0 = *(const float4*)&X[(size_t)gr * IN_FEATS + k0 + cc * 8];
        const float4 f1 = *(const float4*)&X[(size_t)gr * IN_FEATS + k0 + cc * 8 + 4];
        union { ushort u[8]; short8 s; } t;
        t.u[0] = f2bf(f0.x); t.u[1] = f2bf(f0.y); t.u[2] = f2bf(f0.z); t.u[3] = f2bf(f0.w);
        t.u[4] = f2bf(f1.x); t.u[5] = f2bf(f1.y); t.u[6] = f2bf(f1.z); t.u[7] = f2bf(f1.w);
        v = t.s;
      }
      ar[ii] = v;
      br[ii] = *(const short8*)&Bt[(size_t)(col0 + r) * IN_FEATS + k0 + cc * 8];
    }
    __syncthreads();
    #pragma unroll
    for (int ii = 0; ii < 4; ++ii) {
      int ch = ii * 256 + tid;
      int r = ch >> 3, cc = ch & 7;
      *(short8*)&As[r][cc * 8] = ar[ii];
      *(short8*)&Bs[r][cc * 8] = br[ii];
    }
    __syncthreads();
    #pragma unroll
    for (int ks = 0; ks < 2; ++ks) {
      const int kb = ks * 32 + kq * 8;
      short8 af[4], bf[4];
      #pragma unroll
      for (int i = 0; i < 4; ++i) af[i] = *(const short8*)&As[wr * 64 + i * 16 + lr][kb];
      #pragma unroll
      for (int j = 0; j < 4; ++j) bf[j] = *(const short8*)&Bs[wc * 64 + j * 16 + lr][kb];
      #pragma unroll
      for (int i = 0; i < 4; ++i)
        #pragma unroll
        for (int j = 0; j < 4; ++j)
          acc[i][j] = __builtin_amdgcn_mfma_f32_16x16x32_bf16(af[i], bf[j], acc[i][j], 0, 0, 0);
    }
  }

  // epilogue 1: h bf16
  #pragma unroll
  for (int i = 0; i < 4; ++i) {
    int rbase = row0 + wr * 64 + i * 16 + kq * 4;
    #pragma unroll
    for (int j = 0; j < 4; ++j) {
      int cc = col0 + wc * 64 + j * 16 + lr;
      #pragma unroll
      for (int reg = 0; reg < 4; ++reg) {
        int r = rbase + reg;
        if (r < M) hb[(size_t)r * F_TOT + cc] = f2bf(acc[i][j][reg]);
      }
    }
  }

  // epilogue 2: hl/hr
  const int head = cb * 2 + wc;
  float alv[4], arv[4];
  #pragma unroll
  for (int j = 0; j < 4; ++j) {
    alv[j] = a_l[head * OUT_FEATS + j * 16 + lr];
    arv[j] = a_r[head * OUT_FEATS + j * 16 + lr];
  }
  #pragma unroll
  for (int i = 0; i < 4; ++i) {
    #pragma unroll
    for (int reg = 0; reg < 4; ++reg) {
      float pl = 0.f, pr = 0.f;
      #pragma unroll
      for (int j = 0; j < 4; ++j) {
        pl = fmaf(acc[i][j][reg], alv[j], pl);
        pr = fmaf(acc[i][j][reg], arv[j], pr);
      }
      #pragma unroll
      for (int d = 8; d >= 1; d >>= 1) {
        pl += __shfl_xor(pl, d);
        pr += __shfl_xor(pr, d);
      }
      if (lr == 0) {
        int r = row0 + wr * 64 + i * 16 + kq * 4 + reg;
        if (r < M) {
          hl[r * NHEAD + head] = pl;
          hr[r * NHEAD + head] = pr;
        }
      }
    }
  }
}

// ---------------- cooperative CSR: scan1 + scan2 + scan3 + scatter ----------------
__global__ __launch_bounds__(1024) void csr_coop(const int* __restrict__ row,
                                                 const int* __restrict__ col,
                                                 const int* __restrict__ counts,
                                                 int* __restrict__ offsets,
                                                 int* __restrict__ cursor,
                                                 int* __restrict__ col_sorted,
                                                 int* __restrict__ bsum,
                                                 int n, int E, int nblk) {
  cg::grid_group grid = cg::this_grid();
  __shared__ int wsum[16];
  __shared__ int s0;
  const int tid = threadIdx.x;
  const int lane = tid & 63;
  const int wid = tid >> 6;
  const int bid = blockIdx.x;
  const int nthreads = gridDim.x * 1024;
  const int gtid = bid * 1024 + tid;

  // phase 1: per-block scan of 1024 counts
  {
    int i = gtid;
    int v = (i < n) ? counts[i] : 0;
    int inc = v;
    #pragma unroll
    for (int d = 1; d < 64; d <<= 1) {
      int t = __shfl_up(inc, d);
      if (lane >= d) inc += t;
    }
    if (lane == 63) wsum[wid] = inc;
    __syncthreads();
    if (tid < 16) {
      int x = wsum[tid];
      #pragma unroll
      for (int d = 1; d < 16; d <<= 1) {
        int t = __shfl_up(x, d);
        if (tid >= d) x += t;
      }
      wsum[tid] = x;
    }
    __syncthreads();
    int excl = ((wid > 0) ? wsum[wid - 1] : 0) + inc - v;
    if (i < n) offsets[i] = excl;
    if (tid == 0) bsum[bid] = wsum[15];
  }
  grid.sync();

  // phase 2: scan block sums (block 0; nblk <= 128)
  if (bid == 0) {
    int v = (tid < nblk) ? bsum[tid] : 0;
    int inc = v;
    #pragma unroll
    for (int d = 1; d < 64; d <<= 1) {
      int t = __shfl_up(inc, d);
      if (lane >= d) inc += t;
    }
    if (tid == 63) s0 = inc;
    __syncthreads();
    if (tid >= 64 && tid < 128) inc += s0;
    if (tid < nblk) bsum[tid] = inc - v;
    if (tid == nblk - 1) bsum[nblk] = inc;
  }
  grid.sync();

  // phase 3: add block offsets
  {
    int i = gtid;
    if (i < n) {
      int off = offsets[i] + bsum[i >> 10];
      offsets[i] = off;
      cursor[i] = off;
    }
    if (i == 0) offsets[n] = bsum[nblk];
  }
  grid.sync();

  // phase 4: scatter
  for (int i = gtid; i < E; i += nthreads) {
    int p = atomicAdd(&cursor[row[i]], 1);
    col_sorted[p] = col[i];
  }
}

// ---------------- aggregation: wave/node, 32-lane rows, 2 edges per pass ----------------
__global__ __launch_bounds__(256) void agg_kernel(const ushort* __restrict__ hb,
                                                  const float* __restrict__ hl,
                                                  const float* __restrict__ hr,
                                                  const int* __restrict__ col_sorted,
                                                  const int* __restrict__ offsets,
                                                  float* __restrict__ out, int n) {
  int node = blockIdx.x * 4 + (threadIdx.x >> 6);
  int lane = threadIdx.x & 63;
  if (node >= n) return;
  const int s = offsets[node];
  const int t = offsets[node + 1];
  const int half = lane >> 5;       // which edge of the pair
  const int fl = lane & 31;         // feature-lane: features [fl*8, fl*8+8)
  const int head = fl >> 3;
  const float hln = hl[node * NHEAD + head];

  // phase 1: parallel max of hr[col] per head (16-lane groups on raw lane)
  float mx = -INFINITY;
  {
    const int li = lane & 15;
    const int hm = lane >> 4;
    for (int i = s + li; i < t; i += 16)
      mx = fmaxf(mx, hr[col_sorted[i] * NHEAD + hm]);
    #pragma unroll
    for (int d = 1; d < 16; d <<= 1) mx = fmaxf(mx, __shfl_xor(mx, d));
  }
  float mh = __shfl(mx, head << 4);   // max for MY head
  float e0 = hln + mh;
  const float m = e0 > 0.f ? e0 : ALPHA * e0;

  // phase 2: fixed-m accumulate; each half-wave owns alternating edges
  float denom = 0.f;
  float a[8] = {0.f, 0.f, 0.f, 0.f, 0.f, 0.f, 0.f, 0.f};
  const size_t fo = (size_t)fl * 8;

  auto edge = [&](int ii) {
    const int c = col_sorted[ii];
    const float g = hr[c * NHEAD + head];
    union { ush8 v; ushort u[8]; } hv;
    hv.v = *(const ush8*)&hb[(size_t)c * F_TOT + fo];
    float ee = hln + g;
    ee = ee > 0.f ? ee : ALPHA * ee;
    const float w = __expf(ee - m);
    denom += w;
    #pragma unroll
    for (int j = 0; j < 8; ++j) a[j] = fmaf(w, bf2f(hv.u[j]), a[j]);
  };

  int i = s + half;
  for (; i + 6 < t; i += 8) { edge(i); edge(i + 2); edge(i + 4); edge(i + 6); }
  for (; i < t; i += 2) edge(i);

  // cross-half reduce (lanes l and l^32 share fl)
  denom += __shfl_xor(denom, 32);
  #pragma unroll
  for (int j = 0; j < 8; ++j) a[j] += __shfl_xor(a[j], 32);

  const float inv = 1.f / (denom + 1e-16f);
  float4 o = make_float4(a[half * 4 + 0] * inv, a[half * 4 + 1] * inv,
                         a[half * 4 + 2] * inv, a[half * 4 + 3] * inv);
  *(float4*)&out[(size_t)node * F_TOT + fl * 8 + half * 4] = o;
}

// ---------------- launcher ----------------
extern "C" void kernel_launch(void* const* d_in, const int* in_sizes, int n_in,
                              void* d_out, int out_size, void* d_ws, size_t ws_size,
                              hipStream_t stream) {
  const float* x   = (const float*)d_in[0];
  const float* W   = (const float*)d_in[1];
  const float* a_l = (const float*)d_in[2];
  const float* a_r = (const float*)d_in[3];
  const int*   row = (const int*)d_in[4];
  const int*   col = (const int*)d_in[5];
  float* out = (float*)d_out;

  int n = in_sizes[0] / IN_FEATS;   // 100000
  int E = in_sizes[4];              // 1600000

  char* ws = (char*)d_ws;
  ushort* hb      = (ushort*)(ws + OFF_HB);
  float*  hl      = (float*)(ws + OFF_HL);
  float*  hr      = (float*)(ws + OFF_HR);
  int* counts     = (int*)(ws + OFF_CNT);
  int* offsets    = (int*)(ws + OFF_OFFS);
  int* cursor     = (int*)(ws + OFF_CUR);
  int* col_sorted = (int*)(ws + OFF_CSORT);
  int* bsum       = (int*)(ws + OFF_BSUM);
  ushort* Wt      = (ushort*)(ws + OFF_WT);

  // 1. W transpose+cast
  castT_W_kernel<<<16, 256, 0, stream>>>(W, Wt);
  // 2. zero counts
  hipMemsetAsync(counts, 0, (size_t)(n + 1) * sizeof(int), stream);
  // 3. fused GEMM + hist (hist = blocks [0,512), gemm = pair-swizzled 1568)
  gemm_hist<<<HIST_BLKS + 1568, 256, 0, stream>>>(x, Wt, hb, a_l, a_r, hl, hr, n,
                                                  row, counts, E);
  // 4. cooperative CSR build
  int nblk = (n + 1023) / 1024;  // 98
  void* cargs[] = {(void*)&row, (void*)&col, (void*)&counts, (void*)&offsets,
                   (void*)&cursor, (void*)&col_sorted, (void*)&bsum,
                   (void*)&n, (void*)&E, (void*)&nblk};
  hipLaunchCooperativeKernel((const void*)csr_coop, dim3(nblk), dim3(1024),
                             cargs, 0, stream);
  // 5. aggregation
  agg_kernel<<<(n + 3) / 4, 256, 0, stream>>>(hb, hl, hr, col_sorted, offsets, out, n);
}

// Round 5
// 430.088 us; speedup vs baseline: 1.0013x; 1.0013x over previous
//
#include <hip/hip_runtime.h>
#include <hip/hip_bf16.h>
#include <hip/hip_cooperative_groups.h>
#include <math.h>

namespace cg = cooperative_groups;

#define N_NODES 100000
#define N_EDGES 1600000
#define IN_FEATS 256
#define OUT_FEATS 64
#define NHEAD 4
#define F_TOT 256
#define ALPHA 0.2f

typedef __attribute__((ext_vector_type(8))) short short8;
typedef __attribute__((ext_vector_type(8))) unsigned short ush8;
typedef __attribute__((ext_vector_type(4))) float f32x4;

// ---------------- workspace layout (bytes) ----------------
#define OFF_HB    ((size_t)0)            // 51,200,000
#define OFF_HL    ((size_t)51200000)     // 1,600,000
#define OFF_HR    ((size_t)52800000)     // 1,600,000
#define OFF_CNT   ((size_t)54400000)     // 400,128
#define OFF_OFFS  ((size_t)54800128)     // 400,128
#define OFF_CUR   ((size_t)55200256)     // 400,128
#define OFF_CSORT ((size_t)55600384)     // 6,400,000
#define OFF_BSUM  ((size_t)62000384)     // 512
#define OFF_WT    ((size_t)62000896)     // 131,072

__device__ inline float bf2f(ushort u) { return __uint_as_float((uint)u << 16); }
__device__ inline ushort f2bf(float f) {
  __hip_bfloat16 b = __float2bfloat16(f);
  return *(ushort*)&b;
}

// ---------------- prep: W transpose/cast (blocks 0-15) + hist (blocks 16+) ----------------
#define PREP_CAST_BLKS 16
#define PREP_HIST_BLKS 512

__global__ __launch_bounds__(256) void prep_kernel(const float* __restrict__ W,
                                                   ushort* __restrict__ Wt,
                                                   const int* __restrict__ row,
                                                   int* __restrict__ counts, int E) {
  if (blockIdx.x < PREP_CAST_BLKS) {
    __shared__ float s[64][65];
    const int bi = blockIdx.x & 3;
    const int bj = blockIdx.x >> 2;
    const int tid = threadIdx.x;
    const int n0 = bi * 64, k0 = bj * 64;
    #pragma unroll
    for (int it = 0; it < 16; ++it) {
      int idx = it * 256 + tid;
      int r = idx >> 6, c = idx & 63;
      s[c][r] = W[(size_t)(k0 + r) * F_TOT + n0 + c];
    }
    __syncthreads();
    #pragma unroll
    for (int it = 0; it < 16; ++it) {
      int idx = it * 256 + tid;
      int nn = idx >> 6, kk = idx & 63;
      Wt[(size_t)(n0 + nn) * IN_FEATS + k0 + kk] = f2bf(s[nn][kk]);
    }
  } else {
    int gtid = (blockIdx.x - PREP_CAST_BLKS) * 256 + threadIdx.x;
    for (int i = gtid; i < E; i += PREP_HIST_BLKS * 256)
      atomicAdd(&counts[row[i]], 1);
  }
}

// ---------------- MFMA GEMM: BM=128, BN=256 (full N), 512 thr / 8 waves ----------------
#define GBM 128
#define GBK 64
#define NRBLK 782   // ceil(100000/128)

__global__ __launch_bounds__(512) void gemm_bf16(const float* __restrict__ X,
                                                 const ushort* __restrict__ Bt,  // Wt [256][256]
                                                 ushort* __restrict__ hb,
                                                 const float* __restrict__ a_l,
                                                 const float* __restrict__ a_r,
                                                 float* __restrict__ hl,
                                                 float* __restrict__ hr, int M) {
  __shared__ __align__(16) ushort As[GBM][GBK + 8];   // 18,432 B
  __shared__ __align__(16) ushort Bs[F_TOT][GBK + 8]; // 36,864 B
  const int row0 = blockIdx.x * GBM;
  const int tid = threadIdx.x;
  const int lane = tid & 63;
  const int wid = tid >> 6;        // 0..7
  const int wr = wid >> 2;         // 0..1  (row half)
  const int wc = wid & 3;          // 0..3  (col quarter == head)
  const int lr = lane & 15;
  const int kq = lane >> 4;

  f32x4 acc[4][4];
  #pragma unroll
  for (int i = 0; i < 4; ++i)
    #pragma unroll
    for (int j = 0; j < 4; ++j) acc[i][j] = (f32x4)(0.f);

  for (int k0 = 0; k0 < IN_FEATS; k0 += GBK) {
    // A: 128 rows x 64 k f32 -> cast. 512 segs of 16 floats; seg = tid.
    {
      const int r = tid >> 2;          // 0..127
      const int sc = (tid & 3) * 16;   // 0,16,32,48
      const int gr = row0 + r;
      union { ushort u[16]; short8 s[2]; } t;
      if (gr < M) {
        const float* src = &X[(size_t)gr * IN_FEATS + k0 + sc];
        const float4 f0 = *(const float4*)(src);
        const float4 f1 = *(const float4*)(src + 4);
        const float4 f2 = *(const float4*)(src + 8);
        const float4 f3 = *(const float4*)(src + 12);
        t.u[0] = f2bf(f0.x);  t.u[1] = f2bf(f0.y);  t.u[2] = f2bf(f0.z);  t.u[3] = f2bf(f0.w);
        t.u[4] = f2bf(f1.x);  t.u[5] = f2bf(f1.y);  t.u[6] = f2bf(f1.z);  t.u[7] = f2bf(f1.w);
        t.u[8] = f2bf(f2.x);  t.u[9] = f2bf(f2.y);  t.u[10] = f2bf(f2.z); t.u[11] = f2bf(f2.w);
        t.u[12] = f2bf(f3.x); t.u[13] = f2bf(f3.y); t.u[14] = f2bf(f3.z); t.u[15] = f2bf(f3.w);
      } else {
        t.s[0] = (short8)(0); t.s[1] = (short8)(0);
      }
      __syncthreads();   // protect LDS reuse from previous iteration
      *(short8*)&As[r][sc] = t.s[0];
      *(short8*)&As[r][sc + 8] = t.s[1];
    }
    // B: 256 rows x 64 k bf16. 2048 short8; 4 per thread.
    #pragma unroll
    for (int it = 0; it < 4; ++it) {
      int idx = it * 512 + tid;
      int r = idx >> 3, c8 = (idx & 7) * 8;
      *(short8*)&Bs[r][c8] = *(const short8*)&Bt[(size_t)r * IN_FEATS + k0 + c8];
    }
    __syncthreads();
    #pragma unroll
    for (int ks = 0; ks < 2; ++ks) {
      const int kb = ks * 32 + kq * 8;
      short8 af[4], bf[4];
      #pragma unroll
      for (int i = 0; i < 4; ++i) af[i] = *(const short8*)&As[wr * 64 + i * 16 + lr][kb];
      #pragma unroll
      for (int j = 0; j < 4; ++j) bf[j] = *(const short8*)&Bs[wc * 64 + j * 16 + lr][kb];
      #pragma unroll
      for (int i = 0; i < 4; ++i)
        #pragma unroll
        for (int j = 0; j < 4; ++j)
          acc[i][j] = __builtin_amdgcn_mfma_f32_16x16x32_bf16(af[i], bf[j], acc[i][j], 0, 0, 0);
    }
  }

  // epilogue 1: h bf16.  C mapping: col=lane&15, row=(lane>>4)*4+reg
  #pragma unroll
  for (int i = 0; i < 4; ++i) {
    int rbase = row0 + wr * 64 + i * 16 + kq * 4;
    #pragma unroll
    for (int j = 0; j < 4; ++j) {
      int cc = wc * 64 + j * 16 + lr;
      #pragma unroll
      for (int reg = 0; reg < 4; ++reg) {
        int r = rbase + reg;
        if (r < M) hb[(size_t)r * F_TOT + cc] = f2bf(acc[i][j][reg]);
      }
    }
  }

  // epilogue 2: hl/hr (wave's 64 cols == head wc)
  const int head = wc;
  float alv[4], arv[4];
  #pragma unroll
  for (int j = 0; j < 4; ++j) {
    alv[j] = a_l[head * OUT_FEATS + j * 16 + lr];
    arv[j] = a_r[head * OUT_FEATS + j * 16 + lr];
  }
  #pragma unroll
  for (int i = 0; i < 4; ++i) {
    #pragma unroll
    for (int reg = 0; reg < 4; ++reg) {
      float pl = 0.f, pr = 0.f;
      #pragma unroll
      for (int j = 0; j < 4; ++j) {
        pl = fmaf(acc[i][j][reg], alv[j], pl);
        pr = fmaf(acc[i][j][reg], arv[j], pr);
      }
      #pragma unroll
      for (int d = 8; d >= 1; d >>= 1) {
        pl += __shfl_xor(pl, d);
        pr += __shfl_xor(pr, d);
      }
      if (lr == 0) {
        int r = row0 + wr * 64 + i * 16 + kq * 4 + reg;
        if (r < M) {
          hl[r * NHEAD + head] = pl;
          hr[r * NHEAD + head] = pr;
        }
      }
    }
  }
}

// ---------------- cooperative CSR: scan + scatter ----------------
__global__ __launch_bounds__(1024) void csr_coop(const int* __restrict__ row,
                                                 const int* __restrict__ col,
                                                 const int* __restrict__ counts,
                                                 int* __restrict__ offsets,
                                                 int* __restrict__ cursor,
                                                 int* __restrict__ col_sorted,
                                                 int* __restrict__ bsum,
                                                 int n, int E, int nblk) {
  cg::grid_group grid = cg::this_grid();
  __shared__ int wsum[16];
  __shared__ int s0;
  const int tid = threadIdx.x;
  const int lane = tid & 63;
  const int wid = tid >> 6;
  const int bid = blockIdx.x;
  const int nthreads = gridDim.x * 1024;
  const int gtid = bid * 1024 + tid;

  {
    int i = gtid;
    int v = (i < n) ? counts[i] : 0;
    int inc = v;
    #pragma unroll
    for (int d = 1; d < 64; d <<= 1) {
      int t = __shfl_up(inc, d);
      if (lane >= d) inc += t;
    }
    if (lane == 63) wsum[wid] = inc;
    __syncthreads();
    if (tid < 16) {
      int x = wsum[tid];
      #pragma unroll
      for (int d = 1; d < 16; d <<= 1) {
        int t = __shfl_up(x, d);
        if (tid >= d) x += t;
      }
      wsum[tid] = x;
    }
    __syncthreads();
    int excl = ((wid > 0) ? wsum[wid - 1] : 0) + inc - v;
    if (i < n) offsets[i] = excl;
    if (tid == 0) bsum[bid] = wsum[15];
  }
  grid.sync();

  if (bid == 0) {
    int v = (tid < nblk) ? bsum[tid] : 0;
    int inc = v;
    #pragma unroll
    for (int d = 1; d < 64; d <<= 1) {
      int t = __shfl_up(inc, d);
      if (lane >= d) inc += t;
    }
    if (tid == 63) s0 = inc;
    __syncthreads();
    if (tid >= 64 && tid < 128) inc += s0;
    if (tid < nblk) bsum[tid] = inc - v;
    if (tid == nblk - 1) bsum[nblk] = inc;
  }
  grid.sync();

  {
    int i = gtid;
    if (i < n) {
      int off = offsets[i] + bsum[i >> 10];
      offsets[i] = off;
      cursor[i] = off;
    }
    if (i == 0) offsets[n] = bsum[nblk];
  }
  grid.sync();

  for (int i = gtid; i < E; i += nthreads) {
    int p = atomicAdd(&cursor[row[i]], 1);
    col_sorted[p] = col[i];
  }
}

// ---------------- aggregation: wave/node, 32-lane rows, 2 edges per pass ----------------
__global__ __launch_bounds__(256) void agg_kernel(const ushort* __restrict__ hb,
                                                  const float* __restrict__ hl,
                                                  const float* __restrict__ hr,
                                                  const int* __restrict__ col_sorted,
                                                  const int* __restrict__ offsets,
                                                  float* __restrict__ out, int n) {
  int node = blockIdx.x * 4 + (threadIdx.x >> 6);
  int lane = threadIdx.x & 63;
  if (node >= n) return;
  const int s = offsets[node];
  const int t = offsets[node + 1];
  const int half = lane >> 5;
  const int fl = lane & 31;
  const int head = fl >> 3;
  const float hln = hl[node * NHEAD + head];

  float mx = -INFINITY;
  {
    const int li = lane & 15;
    const int hm = lane >> 4;
    for (int i = s + li; i < t; i += 16)
      mx = fmaxf(mx, hr[col_sorted[i] * NHEAD + hm]);
    #pragma unroll
    for (int d = 1; d < 16; d <<= 1) mx = fmaxf(mx, __shfl_xor(mx, d));
  }
  float mh = __shfl(mx, head << 4);
  float e0 = hln + mh;
  const float m = e0 > 0.f ? e0 : ALPHA * e0;

  float denom = 0.f;
  float a[8] = {0.f, 0.f, 0.f, 0.f, 0.f, 0.f, 0.f, 0.f};
  const size_t fo = (size_t)fl * 8;

  auto edge = [&](int ii) {
    const int c = col_sorted[ii];
    const float g = hr[c * NHEAD + head];
    union { ush8 v; ushort u[8]; } hv;
    hv.v = *(const ush8*)&hb[(size_t)c * F_TOT + fo];
    float ee = hln + g;
    ee = ee > 0.f ? ee : ALPHA * ee;
    const float w = __expf(ee - m);
    denom += w;
    #pragma unroll
    for (int j = 0; j < 8; ++j) a[j] = fmaf(w, bf2f(hv.u[j]), a[j]);
  };

  int i = s + half;
  for (; i + 6 < t; i += 8) { edge(i); edge(i + 2); edge(i + 4); edge(i + 6); }
  for (; i < t; i += 2) edge(i);

  denom += __shfl_xor(denom, 32);
  #pragma unroll
  for (int j = 0; j < 8; ++j) a[j] += __shfl_xor(a[j], 32);

  const float inv = 1.f / (denom + 1e-16f);
  float4 o = make_float4(a[half * 4 + 0] * inv, a[half * 4 + 1] * inv,
                         a[half * 4 + 2] * inv, a[half * 4 + 3] * inv);
  *(float4*)&out[(size_t)node * F_TOT + fl * 8 + half * 4] = o;
}

// ---------------- launcher ----------------
extern "C" void kernel_launch(void* const* d_in, const int* in_sizes, int n_in,
                              void* d_out, int out_size, void* d_ws, size_t ws_size,
                              hipStream_t stream) {
  const float* x   = (const float*)d_in[0];
  const float* W   = (const float*)d_in[1];
  const float* a_l = (const float*)d_in[2];
  const float* a_r = (const float*)d_in[3];
  const int*   row = (const int*)d_in[4];
  const int*   col = (const int*)d_in[5];
  float* out = (float*)d_out;

  int n = in_sizes[0] / IN_FEATS;   // 100000
  int E = in_sizes[4];              // 1600000

  char* ws = (char*)d_ws;
  ushort* hb      = (ushort*)(ws + OFF_HB);
  float*  hl      = (float*)(ws + OFF_HL);
  float*  hr      = (float*)(ws + OFF_HR);
  int* counts     = (int*)(ws + OFF_CNT);
  int* offsets    = (int*)(ws + OFF_OFFS);
  int* cursor     = (int*)(ws + OFF_CUR);
  int* col_sorted = (int*)(ws + OFF_CSORT);
  int* bsum       = (int*)(ws + OFF_BSUM);
  ushort* Wt      = (ushort*)(ws + OFF_WT);

  // 1. zero counts
  hipMemsetAsync(counts, 0, (size_t)(n + 1) * sizeof(int), stream);
  // 2. prep: W transpose/cast + histogram
  prep_kernel<<<PREP_CAST_BLKS + PREP_HIST_BLKS, 256, 0, stream>>>(W, Wt, row, counts, E);
  // 3. GEMM (full-N blocks; x read exactly once) + fused hl/hr epilogue
  gemm_bf16<<<NRBLK, 512, 0, stream>>>(x, Wt, hb, a_l, a_r, hl, hr, n);
  // 4. cooperative CSR build
  int nblk = (n + 1023) / 1024;  // 98
  void* cargs[] = {(void*)&row, (void*)&col, (void*)&counts, (void*)&offsets,
                   (void*)&cursor, (void*)&col_sorted, (void*)&bsum,
                   (void*)&n, (void*)&E, (void*)&nblk};
  hipLaunchCooperativeKernel((const void*)csr_coop, dim3(nblk), dim3(1024),
                             cargs, 0, stream);
  // 5. aggregation
  agg_kernel<<<(n + 3) / 4, 256, 0, stream>>>(hb, hl, hr, col_sorted, offsets, out, n);
}

// Round 6
// 389.694 us; speedup vs baseline: 1.1051x; 1.1037x over previous
//
#include <hip/hip_runtime.h>
#include <hip/hip_bf16.h>
#include <math.h>

#define N_NODES 100000
#define N_EDGES 1600000
#define IN_FEATS 256
#define OUT_FEATS 64
#define NHEAD 4
#define F_TOT 256
#define ALPHA 0.2f

typedef __attribute__((ext_vector_type(8))) short short8;
typedef __attribute__((ext_vector_type(8))) unsigned short ush8;
typedef __attribute__((ext_vector_type(4))) float f32x4;

// ---------------- workspace layout (bytes) ----------------
#define OFF_HB    ((size_t)0)            // 51,200,000
#define OFF_HL    ((size_t)51200000)     // 1,600,000
#define OFF_HR    ((size_t)52800000)     // 1,600,000
#define OFF_CNT   ((size_t)54400000)     // 400,128
#define OFF_OFFS  ((size_t)54800128)     // 400,128
#define OFF_CUR   ((size_t)55200256)     // 400,128
#define OFF_CSORT ((size_t)55600384)     // 6,400,000
#define OFF_ESORT ((size_t)62000384)     // 25,600,000 (E * 16B, 16-aligned)
#define OFF_BSUM  ((size_t)87600384)     // 4,096
#define OFF_WT    ((size_t)87604480)     // 131,072
// total ~87.7 MB

__device__ inline float bf2f(ushort u) { return __uint_as_float((uint)u << 16); }
__device__ inline ushort f2bf(float f) {
  __hip_bfloat16 b = __float2bfloat16(f);
  return *(ushort*)&b;
}

// ---------------- prep: W transpose/cast (blocks 0-15) + hist (blocks 16+) ----------------
#define PREP_CAST_BLKS 16
#define PREP_HIST_BLKS 512

__global__ __launch_bounds__(256) void prep_kernel(const float* __restrict__ W,
                                                   ushort* __restrict__ Wt,
                                                   const int* __restrict__ row,
                                                   int* __restrict__ counts, int E) {
  if (blockIdx.x < PREP_CAST_BLKS) {
    __shared__ float s[64][65];
    const int bi = blockIdx.x & 3;
    const int bj = blockIdx.x >> 2;
    const int tid = threadIdx.x;
    const int n0 = bi * 64, k0 = bj * 64;
    #pragma unroll
    for (int it = 0; it < 16; ++it) {
      int idx = it * 256 + tid;
      int r = idx >> 6, c = idx & 63;
      s[c][r] = W[(size_t)(k0 + r) * F_TOT + n0 + c];
    }
    __syncthreads();
    #pragma unroll
    for (int it = 0; it < 16; ++it) {
      int idx = it * 256 + tid;
      int nn = idx >> 6, kk = idx & 63;
      Wt[(size_t)(n0 + nn) * IN_FEATS + k0 + kk] = f2bf(s[nn][kk]);
    }
  } else {
    int gtid = (blockIdx.x - PREP_CAST_BLKS) * 256 + threadIdx.x;
    for (int i = gtid; i < E; i += PREP_HIST_BLKS * 256)
      atomicAdd(&counts[row[i]], 1);
  }
}

// ---------------- MFMA GEMM: BM=128, BN=256 (full N), 512 thr / 8 waves ----------------
#define GBM 128
#define GBK 64
#define NRBLK 782   // ceil(100000/128)

__global__ __launch_bounds__(512) void gemm_bf16(const float* __restrict__ X,
                                                 const ushort* __restrict__ Bt,  // Wt [256][256]
                                                 ushort* __restrict__ hb,
                                                 const float* __restrict__ a_l,
                                                 const float* __restrict__ a_r,
                                                 float* __restrict__ hl,
                                                 float* __restrict__ hr, int M) {
  __shared__ __align__(16) ushort As[GBM][GBK + 8];
  __shared__ __align__(16) ushort Bs[F_TOT][GBK + 8];
  const int row0 = blockIdx.x * GBM;
  const int tid = threadIdx.x;
  const int lane = tid & 63;
  const int wid = tid >> 6;
  const int wr = wid >> 2;
  const int wc = wid & 3;
  const int lr = lane & 15;
  const int kq = lane >> 4;

  f32x4 acc[4][4];
  #pragma unroll
  for (int i = 0; i < 4; ++i)
    #pragma unroll
    for (int j = 0; j < 4; ++j) acc[i][j] = (f32x4)(0.f);

  for (int k0 = 0; k0 < IN_FEATS; k0 += GBK) {
    {
      const int r = tid >> 2;
      const int sc = (tid & 3) * 16;
      const int gr = row0 + r;
      union { ushort u[16]; short8 s[2]; } t;
      if (gr < M) {
        const float* src = &X[(size_t)gr * IN_FEATS + k0 + sc];
        const float4 f0 = *(const float4*)(src);
        const float4 f1 = *(const float4*)(src + 4);
        const float4 f2 = *(const float4*)(src + 8);
        const float4 f3 = *(const float4*)(src + 12);
        t.u[0] = f2bf(f0.x);  t.u[1] = f2bf(f0.y);  t.u[2] = f2bf(f0.z);  t.u[3] = f2bf(f0.w);
        t.u[4] = f2bf(f1.x);  t.u[5] = f2bf(f1.y);  t.u[6] = f2bf(f1.z);  t.u[7] = f2bf(f1.w);
        t.u[8] = f2bf(f2.x);  t.u[9] = f2bf(f2.y);  t.u[10] = f2bf(f2.z); t.u[11] = f2bf(f2.w);
        t.u[12] = f2bf(f3.x); t.u[13] = f2bf(f3.y); t.u[14] = f2bf(f3.z); t.u[15] = f2bf(f3.w);
      } else {
        t.s[0] = (short8)(0); t.s[1] = (short8)(0);
      }
      __syncthreads();
      *(short8*)&As[r][sc] = t.s[0];
      *(short8*)&As[r][sc + 8] = t.s[1];
    }
    #pragma unroll
    for (int it = 0; it < 4; ++it) {
      int idx = it * 512 + tid;
      int r = idx >> 3, c8 = (idx & 7) * 8;
      *(short8*)&Bs[r][c8] = *(const short8*)&Bt[(size_t)r * IN_FEATS + k0 + c8];
    }
    __syncthreads();
    #pragma unroll
    for (int ks = 0; ks < 2; ++ks) {
      const int kb = ks * 32 + kq * 8;
      short8 af[4], bf[4];
      #pragma unroll
      for (int i = 0; i < 4; ++i) af[i] = *(const short8*)&As[wr * 64 + i * 16 + lr][kb];
      #pragma unroll
      for (int j = 0; j < 4; ++j) bf[j] = *(const short8*)&Bs[wc * 64 + j * 16 + lr][kb];
      #pragma unroll
      for (int i = 0; i < 4; ++i)
        #pragma unroll
        for (int j = 0; j < 4; ++j)
          acc[i][j] = __builtin_amdgcn_mfma_f32_16x16x32_bf16(af[i], bf[j], acc[i][j], 0, 0, 0);
    }
  }

  // epilogue 1: h bf16
  #pragma unroll
  for (int i = 0; i < 4; ++i) {
    int rbase = row0 + wr * 64 + i * 16 + kq * 4;
    #pragma unroll
    for (int j = 0; j < 4; ++j) {
      int cc = wc * 64 + j * 16 + lr;
      #pragma unroll
      for (int reg = 0; reg < 4; ++reg) {
        int r = rbase + reg;
        if (r < M) hb[(size_t)r * F_TOT + cc] = f2bf(acc[i][j][reg]);
      }
    }
  }

  // epilogue 2: hl/hr (wave's 64 cols == head wc)
  const int head = wc;
  float alv[4], arv[4];
  #pragma unroll
  for (int j = 0; j < 4; ++j) {
    alv[j] = a_l[head * OUT_FEATS + j * 16 + lr];
    arv[j] = a_r[head * OUT_FEATS + j * 16 + lr];
  }
  #pragma unroll
  for (int i = 0; i < 4; ++i) {
    #pragma unroll
    for (int reg = 0; reg < 4; ++reg) {
      float pl = 0.f, pr = 0.f;
      #pragma unroll
      for (int j = 0; j < 4; ++j) {
        pl = fmaf(acc[i][j][reg], alv[j], pl);
        pr = fmaf(acc[i][j][reg], arv[j], pr);
      }
      #pragma unroll
      for (int d = 8; d >= 1; d >>= 1) {
        pl += __shfl_xor(pl, d);
        pr += __shfl_xor(pr, d);
      }
      if (lr == 0) {
        int r = row0 + wr * 64 + i * 16 + kq * 4 + reg;
        if (r < M) {
          hl[r * NHEAD + head] = pl;
          hr[r * NHEAD + head] = pr;
        }
      }
    }
  }
}

// ---------------- CSR scan (separate small kernels) ----------------
__global__ __launch_bounds__(1024) void scan1_kernel(const int* __restrict__ counts,
                                                     int* __restrict__ offsets,
                                                     int* __restrict__ bsum, int n) {
  __shared__ int wsum[16];
  const int tid = threadIdx.x;
  const int lane = tid & 63;
  const int wid = tid >> 6;
  int i = blockIdx.x * 1024 + tid;
  int v = (i < n) ? counts[i] : 0;
  int inc = v;
  #pragma unroll
  for (int d = 1; d < 64; d <<= 1) {
    int t = __shfl_up(inc, d);
    if (lane >= d) inc += t;
  }
  if (lane == 63) wsum[wid] = inc;
  __syncthreads();
  if (tid < 16) {
    int x = wsum[tid];
    #pragma unroll
    for (int d = 1; d < 16; d <<= 1) {
      int t = __shfl_up(x, d);
      if (tid >= d) x += t;
    }
    wsum[tid] = x;
  }
  __syncthreads();
  int excl = ((wid > 0) ? wsum[wid - 1] : 0) + inc - v;
  if (i < n) offsets[i] = excl;
  if (tid == 0) bsum[blockIdx.x] = wsum[15];
}

__global__ __launch_bounds__(128) void scan2_kernel(int* __restrict__ bsum, int nblk) {
  __shared__ int s0;
  const int tid = threadIdx.x;
  int v = (tid < nblk) ? bsum[tid] : 0;
  int inc = v;
  #pragma unroll
  for (int d = 1; d < 64; d <<= 1) {
    int t = __shfl_up(inc, d);
    if ((tid & 63) >= d) inc += t;
  }
  if (tid == 63) s0 = inc;
  __syncthreads();
  if (tid >= 64 && tid < 128) inc += s0;
  if (tid < nblk) bsum[tid] = inc - v;
  if (tid == nblk - 1) bsum[nblk] = inc;
}

__global__ __launch_bounds__(256) void scan3_kernel(int* __restrict__ offsets,
                                                    int* __restrict__ cursor,
                                                    const int* __restrict__ bsum,
                                                    int n, int nblk) {
  int i = blockIdx.x * blockDim.x + threadIdx.x;
  if (i < n) {
    int off = offsets[i] + bsum[i >> 10];
    offsets[i] = off;
    cursor[i] = off;
  }
  if (i == 0) offsets[n] = bsum[nblk];
}

// ---------------- scatter + per-edge exp weights (no max: scores are O(10) << 88) ----------------
__global__ void scatter_esort(const int* __restrict__ row, const int* __restrict__ col,
                              const float* __restrict__ hl, const float* __restrict__ hr,
                              int* __restrict__ cursor, int* __restrict__ col_sorted,
                              float* __restrict__ esort, int E) {
  int i = blockIdx.x * blockDim.x + threadIdx.x;
  if (i >= E) return;
  const int r = row[i];
  const int c = col[i];
  const float4 l4 = *(const float4*)&hl[r * NHEAD];
  const float4 r4 = *(const float4*)&hr[c * NHEAD];
  float e0 = l4.x + r4.x, e1 = l4.y + r4.y, e2 = l4.z + r4.z, e3 = l4.w + r4.w;
  e0 = e0 > 0.f ? e0 : ALPHA * e0;
  e1 = e1 > 0.f ? e1 : ALPHA * e1;
  e2 = e2 > 0.f ? e2 : ALPHA * e2;
  e3 = e3 > 0.f ? e3 : ALPHA * e3;
  float4 w = make_float4(__expf(e0), __expf(e1), __expf(e2), __expf(e3));
  int p = atomicAdd(&cursor[r], 1);
  col_sorted[p] = c;
  *(float4*)&esort[(size_t)p * 4] = w;
}

// ---------------- aggregation: wave/node, no max phase, sequential weight stream ----------------
__global__ __launch_bounds__(256) void agg_kernel(const ushort* __restrict__ hb,
                                                  const int* __restrict__ col_sorted,
                                                  const float* __restrict__ esort,
                                                  const int* __restrict__ offsets,
                                                  float* __restrict__ out, int n) {
  int node = blockIdx.x * 4 + (threadIdx.x >> 6);
  int lane = threadIdx.x & 63;
  if (node >= n) return;
  const int s = offsets[node];
  const int t = offsets[node + 1];
  const int half = lane >> 5;       // which edge of the pair
  const int fl = lane & 31;         // feature-lane: features [fl*8, fl*8+8)
  const int head = fl >> 3;

  float denom = 0.f;
  float a[8] = {0.f, 0.f, 0.f, 0.f, 0.f, 0.f, 0.f, 0.f};
  const size_t fo = (size_t)fl * 8;

  auto edge = [&](int ii) {
    const int c = col_sorted[ii];
    const float w = esort[(size_t)ii * 4 + head];
    union { ush8 v; ushort u[8]; } hv;
    hv.v = *(const ush8*)&hb[(size_t)c * F_TOT + fo];
    denom += w;
    #pragma unroll
    for (int j = 0; j < 8; ++j) a[j] = fmaf(w, bf2f(hv.u[j]), a[j]);
  };

  int i = s + half;
  for (; i + 6 < t; i += 8) { edge(i); edge(i + 2); edge(i + 4); edge(i + 6); }
  for (; i < t; i += 2) edge(i);

  // cross-half reduce (lanes l and l^32 share fl)
  denom += __shfl_xor(denom, 32);
  #pragma unroll
  for (int j = 0; j < 8; ++j) a[j] += __shfl_xor(a[j], 32);

  const float inv = 1.f / (denom + 1e-16f);
  float4 o = make_float4(a[half * 4 + 0] * inv, a[half * 4 + 1] * inv,
                         a[half * 4 + 2] * inv, a[half * 4 + 3] * inv);
  *(float4*)&out[(size_t)node * F_TOT + fl * 8 + half * 4] = o;
}

// ---------------- launcher ----------------
extern "C" void kernel_launch(void* const* d_in, const int* in_sizes, int n_in,
                              void* d_out, int out_size, void* d_ws, size_t ws_size,
                              hipStream_t stream) {
  const float* x   = (const float*)d_in[0];
  const float* W   = (const float*)d_in[1];
  const float* a_l = (const float*)d_in[2];
  const float* a_r = (const float*)d_in[3];
  const int*   row = (const int*)d_in[4];
  const int*   col = (const int*)d_in[5];
  float* out = (float*)d_out;

  int n = in_sizes[0] / IN_FEATS;   // 100000
  int E = in_sizes[4];              // 1600000

  char* ws = (char*)d_ws;
  ushort* hb      = (ushort*)(ws + OFF_HB);
  float*  hl      = (float*)(ws + OFF_HL);
  float*  hr      = (float*)(ws + OFF_HR);
  int* counts     = (int*)(ws + OFF_CNT);
  int* offsets    = (int*)(ws + OFF_OFFS);
  int* cursor     = (int*)(ws + OFF_CUR);
  int* col_sorted = (int*)(ws + OFF_CSORT);
  float* esort    = (float*)(ws + OFF_ESORT);
  int* bsum       = (int*)(ws + OFF_BSUM);
  ushort* Wt      = (ushort*)(ws + OFF_WT);

  // 1. zero counts
  hipMemsetAsync(counts, 0, (size_t)(n + 1) * sizeof(int), stream);
  // 2. prep: W transpose/cast + histogram
  prep_kernel<<<PREP_CAST_BLKS + PREP_HIST_BLKS, 256, 0, stream>>>(W, Wt, row, counts, E);
  // 3. GEMM (x read once) + fused hl/hr epilogue
  gemm_bf16<<<NRBLK, 512, 0, stream>>>(x, Wt, hb, a_l, a_r, hl, hr, n);
  // 4. CSR scan (separate, fully parallel kernels)
  int nblk = (n + 1023) / 1024;  // 98
  scan1_kernel<<<nblk, 1024, 0, stream>>>(counts, offsets, bsum, n);
  scan2_kernel<<<1, 128, 0, stream>>>(bsum, nblk);
  scan3_kernel<<<(n + 255) / 256, 256, 0, stream>>>(offsets, cursor, bsum, n, nblk);
  // 5. scatter + per-edge exp weights (6250 blocks, one edge per thread)
  scatter_esort<<<(E + 255) / 256, 256, 0, stream>>>(row, col, hl, hr, cursor,
                                                     col_sorted, esort, E);
  // 6. aggregation (pure gather + FMA)
  agg_kernel<<<(n + 3) / 4, 256, 0, stream>>>(hb, col_sorted, esort, offsets, out, n);
}